// Round 1
// baseline (3998.807 us; speedup 1.0000x reference)
//
#include <hip/hip_runtime.h>
#include <hip/hip_bf16.h>

// ---------------------------------------------------------------------------
// RelInteraction pipeline, fp32, round 0 (correctness-first).
// Layouts (all channel-minor for coalescing):
//   fm_t   [b][hw][c]      red   [b][hw][d]
//   filt_dw[n][c*9+ij]     filt_pw[n][d][c]
//   fd     [n][hw][c]      fp    [n][hw][d]
//   so     [p][hw][c2] (c2: 0..511 subj, 512..1023 obj)
//   x0     [p][d*49+hw]    x1,x2 [p][4096]
// ---------------------------------------------------------------------------

namespace {
constexpr int NIM  = 2;
constexpr int NOBJ = 64;
constexpr int NPAIR= 256;
constexpr int CCH  = 512;
constexpr int H = 28, W = 28, HW = 784;
constexpr int PP = 49;                 // 7x7 pool
constexpr int NREL = 51;
constexpr int PDIM = 4096;
constexpr int FLAT = CCH * PP;         // 25088

// workspace offsets in floats
constexpr long OFF_FMT = 0;                                   // 2*784*512
constexpr long OFF_RED = OFF_FMT + (long)NIM * HW * CCH;      // 2*784*512
constexpr long OFF_FDW = OFF_RED + (long)NIM * HW * CCH;      // 64*4608
constexpr long OFF_FPW = OFF_FDW + (long)NOBJ * CCH * 9;      // 64*512*512
constexpr long OFF_FD  = OFF_FPW + (long)NOBJ * CCH * CCH;    // 64*784*512
constexpr long OFF_FP  = OFF_FD  + (long)NOBJ * HW * CCH;     // 64*784*512
constexpr long OFF_X1  = OFF_FP  + (long)NOBJ * HW * CCH;     // 256*4096
constexpr long OFF_X2  = OFF_X1  + (long)NPAIR * PDIM;        // 256*4096
// reuse (lifetimes disjoint):
constexpr long OFF_SO  = OFF_FPW;   // 256*49*1024 = 12.8M <= 16.8M
constexpr long OFF_X0  = OFF_FD;    // 256*25088   =  6.4M <= 25.7M
} // namespace

// --- transpose fmaps (b,c,p) -> fm_t (b,p,c) -------------------------------
__global__ void transpose_k(const float* __restrict__ in, float* __restrict__ out) {
    __shared__ float tile[32][33];
    const int b  = blockIdx.z;
    const int p0 = blockIdx.x * 32, c0 = blockIdx.y * 32;
    const int tx = threadIdx.x, ty = threadIdx.y;
    int p = p0 + tx, c = c0 + ty;
    if (p < HW && c < CCH) tile[ty][tx] = in[((long)b * CCH + c) * HW + p];
    __syncthreads();
    int p2 = p0 + ty, c2 = c0 + tx;
    if (p2 < HW && c2 < CCH) out[((long)b * HW + p2) * CCH + c2] = tile[tx][ty];
}

// --- generic NT GEMM: C[m,n] = act(sum_k A[m,k]*B[n,k] + bias[n]) ----------
// A: (M,K) row-major (lda=K), B: (N,K) row-major (ldb=K).
// TROUT=false: C[m*N+n]; TROUT=true: C[n*M+m]. Batched via blockIdx.z.
template<bool RELU, bool TROUT, bool HAS_BIAS>
__global__ __launch_bounds__(256)
void gemm_nt64(const float* __restrict__ A, const float* __restrict__ B,
               const float* __restrict__ bias, float* __restrict__ C,
               int M, int N, int K, long sA, long sB, long sC) {
    constexpr int BM = 64, BN = 64, BK = 16;
    __shared__ float As[BK][BM];
    __shared__ float Bs[BK][BN];
    A += (long)blockIdx.z * sA;
    B += (long)blockIdx.z * sB;
    C += (long)blockIdx.z * sC;
    const int m0 = blockIdx.x * BM;
    const int n0 = blockIdx.y * BN;
    const int tid  = threadIdx.x;
    const int lrow = tid >> 2;           // 0..63 (tile row for loads)
    const int lk4  = (tid & 3) << 2;     // 0,4,8,12
    const int tm   = (tid & 15) << 2;    // 0..60
    const int tn   = (tid >> 4) << 2;    // 0..60
    const int gma = m0 + lrow;
    const int gnb = n0 + lrow;
    const bool am = (gma < M);
    const bool bn = (gnb < N);
    const float* Ald = A + (long)gma * K + lk4;
    const float* Bld = B + (long)gnb * K + lk4;
    float acc[4][4] = {};
    for (int k0 = 0; k0 < K; k0 += BK) {
        float4 av = make_float4(0.f, 0.f, 0.f, 0.f);
        float4 bv = make_float4(0.f, 0.f, 0.f, 0.f);
        if (am) av = *(const float4*)(Ald + k0);
        if (bn) bv = *(const float4*)(Bld + k0);
        As[lk4 + 0][lrow] = av.x; As[lk4 + 1][lrow] = av.y;
        As[lk4 + 2][lrow] = av.z; As[lk4 + 3][lrow] = av.w;
        Bs[lk4 + 0][lrow] = bv.x; Bs[lk4 + 1][lrow] = bv.y;
        Bs[lk4 + 2][lrow] = bv.z; Bs[lk4 + 3][lrow] = bv.w;
        __syncthreads();
        #pragma unroll
        for (int kk = 0; kk < BK; ++kk) {
            float a[4], b[4];
            #pragma unroll
            for (int i = 0; i < 4; ++i) a[i] = As[kk][tm + i];
            #pragma unroll
            for (int j = 0; j < 4; ++j) b[j] = Bs[kk][tn + j];
            #pragma unroll
            for (int i = 0; i < 4; ++i)
                #pragma unroll
                for (int j = 0; j < 4; ++j)
                    acc[i][j] = fmaf(a[i], b[j], acc[i][j]);
        }
        __syncthreads();
    }
    #pragma unroll
    for (int i = 0; i < 4; ++i) {
        const int m = m0 + tm + i;
        if (m >= M) continue;
        #pragma unroll
        for (int j = 0; j < 4; ++j) {
            const int n = n0 + tn + j;
            if (n >= N) continue;
            float v = acc[i][j];
            if (HAS_BIAS) v += bias[n];
            if (RELU) v = fmaxf(v, 0.f);
            if (TROUT) C[(long)n * M + m] = v;
            else       C[(long)m * N + n] = v;
        }
    }
}

// --- depthwise 3x3 (same, zero-pad), per-object filters --------------------
// fd[n][hw][c] = sum_ij red[im(n)][hw'][c] * fdw[n][c*9 + ij]
__global__ void dwconv_k(const float* __restrict__ red, const float* __restrict__ fdw,
                         const float* __restrict__ rois, float* __restrict__ fd) {
    const int c  = threadIdx.x;      // 0..511
    const int hw = blockIdx.x;       // 0..783
    const int n  = blockIdx.y;       // 0..63
    const int y = hw / W, x = hw % W;
    const int b = (int)rois[n * 5];
    const float* rb = red + (long)b * HW * CCH;
    const float* w  = fdw + (long)n * (CCH * 9) + c * 9;
    float acc = 0.f;
    #pragma unroll
    for (int i = 0; i < 3; ++i) {
        const int yy = y + i - 1;
        if (yy < 0 || yy >= H) continue;
        #pragma unroll
        for (int j = 0; j < 3; ++j) {
            const int xx = x + j - 1;
            if (xx < 0 || xx >= W) continue;
            acc = fmaf(rb[(yy * W + xx) * CCH + c], w[i * 3 + j], acc);
        }
    }
    fd[((long)n * HW + hw) * CCH + c] = acc;
}

// --- ROI align (7x7, bilinear, matches reference exactly) ------------------
// so[p][cell][side*512 + c]; grid (49, 2, 256), block 512
__global__ void roialign_k(const float* __restrict__ fp, const float* __restrict__ rois,
                           const int* __restrict__ rel, float* __restrict__ so) {
    const int c    = threadIdx.x;    // 0..511
    const int cell = blockIdx.x;     // 0..48
    const int side = blockIdx.y;     // 0 subj, 1 obj
    const int p    = blockIdx.z;     // 0..255
    const int o = rel[p * 3 + 1 + side];
    const float* box = rois + o * 5 + 1;
    const float b0 = box[0] / 16.f, b1 = box[1] / 16.f;
    const float b2 = box[2] / 16.f, b3 = box[3] / 16.f;
    const int py = cell / 7, px = cell % 7;
    const float gx = (px + 0.5f) / 7.f, gy = (py + 0.5f) / 7.f;
    float xs = b0 + gx * (b2 - b0);
    float ys = b1 + gy * (b3 - b1);
    xs = fminf(fmaxf(xs, 0.f), (float)(W - 1));
    ys = fminf(fmaxf(ys, 0.f), (float)(H - 1));
    const int x0 = (int)floorf(xs), y0 = (int)floorf(ys);
    const int x1 = min(x0 + 1, W - 1), y1 = min(y0 + 1, H - 1);
    const float wx = xs - (float)x0, wy = ys - (float)y0;
    const float* f = fp + (long)o * HW * CCH;
    const float f00 = f[(y0 * W + x0) * CCH + c];
    const float f01 = f[(y0 * W + x1) * CCH + c];
    const float f10 = f[(y1 * W + x0) * CCH + c];
    const float f11 = f[(y1 * W + x1) * CCH + c];
    const float v = f00 * (1.f - wy) * (1.f - wx) + f01 * (1.f - wy) * wx
                  + f10 * wy * (1.f - wx)         + f11 * wy * wx;
    so[((long)p * PP + cell) * (2 * CCH) + side * CCH + c] = v;
}

extern "C" void kernel_launch(void* const* d_in, const int* in_sizes, int n_in,
                              void* d_out, int out_size, void* d_ws, size_t ws_size,
                              hipStream_t stream) {
    const float* fmaps = (const float*)d_in[0];
    const float* rois  = (const float*)d_in[1];
    const int*   rel   = (const int*)  d_in[2];
    const float* feats = (const float*)d_in[3];
    const float* w_dw  = (const float*)d_in[4];
    const float* b_dw  = (const float*)d_in[5];
    const float* w_pw  = (const float*)d_in[6];
    const float* b_pw  = (const float*)d_in[7];
    const float* w_red = (const float*)d_in[8];
    const float* b_red = (const float*)d_in[9];
    const float* w_rec = (const float*)d_in[10];
    const float* b_rec = (const float*)d_in[11];
    const float* w_fc1 = (const float*)d_in[12];
    const float* b_fc1 = (const float*)d_in[13];
    const float* w_fc2 = (const float*)d_in[14];
    const float* b_fc2 = (const float*)d_in[15];
    const float* w_rel = (const float*)d_in[16];
    const float* b_rel = (const float*)d_in[17];

    float* ws  = (float*)d_ws;
    float* out = (float*)d_out;
    float* fmt = ws + OFF_FMT;
    float* red = ws + OFF_RED;
    float* fdw = ws + OFF_FDW;
    float* fpw = ws + OFF_FPW;
    float* fd  = ws + OFF_FD;
    float* fpb = ws + OFF_FP;
    float* so  = ws + OFF_SO;
    float* x0  = ws + OFF_X0;
    float* x1  = ws + OFF_X1;
    float* x2  = ws + OFF_X2;

    // 1. fmaps (b,c,hw) -> fm_t (b,hw,c)
    transpose_k<<<dim3(25, 16, 2), dim3(32, 32), 0, stream>>>(fmaps, fmt);

    // 2. red[b,hw,d] = relu(fm_t[b] @ w_red^T + b_red)   M=784 N=512 K=512, batch 2
    gemm_nt64<true, false, true><<<dim3(13, 8, 2), 256, 0, stream>>>(
        fmt, w_red, b_red, red, HW, CCH, CCH, (long)HW * CCH, 0, (long)HW * CCH);

    // 3. filt_dw = feats @ w_dw^T + b_dw                 M=64 N=4608 K=512
    gemm_nt64<false, false, true><<<dim3(1, 72, 1), 256, 0, stream>>>(
        feats, w_dw, b_dw, fdw, NOBJ, CCH * 9, CCH, 0, 0, 0);

    // 4. filt_pw = feats @ w_pw^T + b_pw                 M=64 N=262144 K=512
    gemm_nt64<false, false, true><<<dim3(1, 4096, 1), 256, 0, stream>>>(
        feats, w_pw, b_pw, fpw, NOBJ, CCH * CCH, CCH, 0, 0, 0);

    // 5. depthwise 3x3: fd[n,hw,c]
    dwconv_k<<<dim3(HW, NOBJ), CCH, 0, stream>>>(red, fdw, rois, fd);

    // 6. fp[n,hw,d] = relu(fd[n] @ filt_pw[n]^T)         M=784 N=512 K=512, batch 64
    gemm_nt64<true, false, false><<<dim3(13, 8, NOBJ), 256, 0, stream>>>(
        fd, fpw, nullptr, fpb, HW, CCH, CCH,
        (long)HW * CCH, (long)CCH * CCH, (long)HW * CCH);

    // 7. ROI align -> so[p,cell,c2]
    roialign_k<<<dim3(PP, 2, NPAIR), CCH, 0, stream>>>(fpb, rois, rel, so);

    // 8. rec: x0[p, d*49+hw] = so[p] @ w_rec^T + b_rec   M=49 N=512 K=1024, batch 256, transposed out
    gemm_nt64<false, true, true><<<dim3(1, 8, NPAIR), 256, 0, stream>>>(
        so, w_rec, b_rec, x0, PP, CCH, 2 * CCH, (long)PP * 2 * CCH, 0, (long)FLAT);

    // 9. x1 = relu(x0 @ w_fc1^T + b_fc1)                 M=256 N=4096 K=25088
    gemm_nt64<true, false, true><<<dim3(4, 64, 1), 256, 0, stream>>>(
        x0, w_fc1, b_fc1, x1, NPAIR, PDIM, FLAT, 0, 0, 0);

    // 10. x2 = x1 @ w_fc2^T + b_fc2                      M=256 N=4096 K=4096
    gemm_nt64<false, false, true><<<dim3(4, 64, 1), 256, 0, stream>>>(
        x1, w_fc2, b_fc2, x2, NPAIR, PDIM, PDIM, 0, 0, 0);

    // 11. out = x2 @ w_rel^T + b_rel                     M=256 N=51 K=4096
    gemm_nt64<false, false, true><<<dim3(4, 1, 1), 256, 0, stream>>>(
        x2, w_rel, b_rel, out, NPAIR, NREL, PDIM, 0, 0, 0);
}